// Round 8
// baseline (355.007 us; speedup 1.0000x reference)
//
#include <hip/hip_runtime.h>
#include <math.h>

// Shapes (fixed by the problem): b=4, c=512, l=4096, 32 groups.
// Inputs/outputs are float32; internal path: bf16 MFMA for QKV/proj,
// attention S-pass: non-scaled fp8 16x16x32, 1-WAVE blocks (barrier-free),
// attention PV-pass: MX-scaled fp8 32x32x64 (throughput-bound, 2x rate wins).
#define BB 4
#define CC 512
#define LL 4096
#define NG 32
#define CPG 16
#define EPSV 1e-6f

typedef short s16x8 __attribute__((ext_vector_type(8)));
typedef __bf16 bf8v __attribute__((ext_vector_type(8)));
typedef float f32x4 __attribute__((ext_vector_type(4)));
typedef float f32x16 __attribute__((ext_vector_type(16)));
typedef int i32x4 __attribute__((ext_vector_type(4)));
typedef int i32x8 __attribute__((ext_vector_type(8)));
typedef unsigned short u16;
typedef unsigned char u8;

typedef const __attribute__((address_space(1))) void g1_void;
typedef __attribute__((address_space(3))) void l3_void;

// raw barrier / waitcnt (memory clobber = compiler reorder fence, no vmcnt drain)
#define ASM_SBAR() asm volatile("s_barrier" ::: "memory")
#define ASM_WAITV(N) asm volatile("s_waitcnt vmcnt(" #N ")" ::: "memory")

static __device__ __forceinline__ float bf2f(u16 h) {
    unsigned int u = ((unsigned int)h) << 16;
    union { unsigned int u; float f; } c; c.u = u; return c.f;
}
static __device__ __forceinline__ u16 f2bf(float f) {
    union { float f; unsigned int u; } c; c.f = f;
    unsigned int lsb = (c.u >> 16) & 1u;
    c.u += 0x7fffu + lsb;           // round-to-nearest-even
    return (u16)(c.u >> 16);
}
static __device__ __forceinline__ u8 f2fp8(float f) {
    int v = __builtin_amdgcn_cvt_pk_fp8_f32(f, f, 0, false);  // OCP e4m3fn, saturating
    return (u8)(v & 0xff);
}
static __device__ __forceinline__ bf8v ld_bf8(const u16* p) {
    return *reinterpret_cast<const bf8v*>(p);
}
// assemble a 32-byte fp8 operand (v8i32) from two 16-B LDS chunks (global k order)
static __device__ __forceinline__ i32x8 ld32(const u8* plo, const u8* phi) {
    i32x4 lo = *reinterpret_cast<const i32x4*>(plo);
    i32x4 hi = *reinterpret_cast<const i32x4*>(phi);
    return __builtin_shufflevector(lo, hi, 0, 1, 2, 3, 4, 5, 6, 7);
}
// MX-scaled fp8 MFMA with unit scales (e8m0 0x7f = 2^0): runs at the 2x fp8 rate
#define MFMA_SC(a, b, c) \
    __builtin_amdgcn_mfma_scale_f32_32x32x64_f8f6f4(a, b, c, 0, 0, 0, 0x7f, 0, 0x7f)

// async global->LDS; HW writes lds_base + lane*16 (wave-uniform base required)
static __device__ __forceinline__ void gload16(const u16* g, u16* l) {
    __builtin_amdgcn_global_load_lds((g1_void*)g, (l3_void*)l, 16, 0, 0);
}
static __device__ __forceinline__ void gload16b(const u8* g, u8* l) {
    __builtin_amdgcn_global_load_lds((g1_void*)g, (l3_void*)l, 16, 0, 0);
}

// ---------------- weight convert: four 512x512 f32 -> bf16 (rows: q,k,v,p) ----------------
__global__ __launch_bounds__(256) void wconv_kernel(const float* __restrict__ w0,
                                                    const float* __restrict__ w1,
                                                    const float* __restrict__ w2,
                                                    const float* __restrict__ w3,
                                                    u16* __restrict__ wbf) {
    int i = blockIdx.x * 256 + threadIdx.x;      // 0..65535 float4 chunks
    int wsel = blockIdx.y;
    const float* src = (wsel == 0) ? w0 : (wsel == 1) ? w1 : (wsel == 2) ? w2 : w3;
    float4 v = reinterpret_cast<const float4*>(src)[i];
    ushort4 o;
    o.x = f2bf(v.x); o.y = f2bf(v.y); o.z = f2bf(v.z); o.w = f2bf(v.w);
    reinterpret_cast<ushort4*>(wbf + (size_t)wsel * CC * CC)[i] = o;
}

// -------- concat q/k/v biases into one f32[1536] + zero the rowsum buffer --------
__global__ __launch_bounds__(256) void biascat_kernel(const float* __restrict__ bq,
                                                      const float* __restrict__ bk,
                                                      const float* __restrict__ bv,
                                                      float* __restrict__ bcat,
                                                      float* __restrict__ rowsum) {
    int i = blockIdx.x * 256 + threadIdx.x;
    if (i < 3 * CC) {
        float v = (i < CC) ? bq[i] : (i < 2 * CC ? bk[i - CC] : bv[i - 2 * CC]);
        bcat[i] = v;
    }
    if (i < BB * LL) rowsum[i] = 0.f;
}

// ---------------- GroupNorm stats: one block per (group, batch) ----------------
__global__ __launch_bounds__(256) void gn_stats_kernel(const float* __restrict__ x,
                                                       float2* __restrict__ stats) {
    int g = blockIdx.x, b = blockIdx.y, t = threadIdx.x;
    const float4* xp = reinterpret_cast<const float4*>(x + ((size_t)b * CC + (size_t)g * CPG) * LL);
    float s = 0.f, ss = 0.f;
    for (int it = 0; it < 64; ++it) {
        float4 v = xp[it * 256 + t];
        s += v.x + v.y + v.z + v.w;
        ss += v.x * v.x + v.y * v.y + v.z * v.z + v.w * v.w;
    }
    #pragma unroll
    for (int off = 32; off; off >>= 1) { s += __shfl_xor(s, off, 64); ss += __shfl_xor(ss, off, 64); }
    __shared__ float rs[4], rss[4];
    int wave = t >> 6, lane = t & 63;
    if (lane == 0) { rs[wave] = s; rss[wave] = ss; }
    __syncthreads();
    if (t == 0) {
        float S = rs[0] + rs[1] + rs[2] + rs[3];
        float SS = rss[0] + rss[1] + rss[2] + rss[3];
        float mean = S * (1.f / 65536.f);
        float var = SS * (1.f / 65536.f) - mean * mean;
        var = fmaxf(var, 0.f);
        stats[b * NG + g] = make_float2(mean, rsqrtf(var + EPSV));
    }
}

// -------- GroupNorm normalize + transpose: x[b][c][l] f32 -> hT[b][l][c] bf16 --------
__global__ __launch_bounds__(256) void gn_norm_t_kernel(const float* __restrict__ x,
                                                        const float2* __restrict__ stats,
                                                        const float* __restrict__ gsc,
                                                        const float* __restrict__ gbi,
                                                        u16* __restrict__ hT) {
    int lt = blockIdx.x, ct = blockIdx.y, b = blockIdx.z;
    __shared__ u16 tile[64][72];
    int t = threadIdx.x;
    int cl0 = t >> 4, c4 = (t & 15) * 4;
    #pragma unroll
    for (int p = 0; p < 4; ++p) {
        int cl = p * 16 + cl0;
        int cg = ct * 64 + cl;
        float2 st = stats[b * NG + (cg >> 4)];
        float sc = gsc[cg] * st.y;
        float bi = gbi[cg];
        float4 v = *reinterpret_cast<const float4*>(x + ((size_t)b * CC + cg) * LL + lt * 64 + c4);
        tile[cl][c4 + 0] = f2bf((v.x - st.x) * sc + bi);
        tile[cl][c4 + 1] = f2bf((v.y - st.x) * sc + bi);
        tile[cl][c4 + 2] = f2bf((v.z - st.x) * sc + bi);
        tile[cl][c4 + 3] = f2bf((v.w - st.x) * sc + bi);
    }
    __syncthreads();
    int r = t >> 3, c8 = (t & 7) * 8;
    #pragma unroll
    for (int p = 0; p < 2; ++p) {
        int ll = p * 32 + r;
        s16x8 ov;
        #pragma unroll
        for (int j = 0; j < 8; ++j) ov[j] = (short)tile[c8 + j][ll];
        u16* hp = hT + ((size_t)b * LL + lt * 64 + ll) * CC + ct * 64 + c8;
        *reinterpret_cast<s16x8*>(hp) = ov;
    }
}

// ---------------- bf16 GEMM: Out = A * B^T + bias ----------------
// MODE 0: fused QKV, fp8 outputs. nt/4==0 -> q8 [l][c], ==1 -> k8 [l][c],
//         ==2 -> v8 stored TRANSPOSED [c][l].
// MODE 3: proj: + bias, TRANSPOSED f32 store with residual: fout = xres + val.
// K-loop: 3 LDS buffers, prefetch distance 2 -> ONE barrier per K-step.
template <int MODE>
__global__ __launch_bounds__(256) void gemm_kernel(const u16* __restrict__ A, size_t asb, int lda,
                                                   const u16* __restrict__ B, size_t bsb, int ldb,
                                                   const float* __restrict__ bias,
                                                   u8* __restrict__ Oq, u8* __restrict__ Ok,
                                                   u8* __restrict__ Ov, size_t osb,
                                                   const float* __restrict__ xres,
                                                   float* __restrict__ fout, int K) {
    // staging 3 x (A 8KB @ b*4096 u16, B 8KB @ 12288+b*4096 u16) = 48 KB;
    // epilogues (fp8 tile 18432 B / bf16 tile 34816 B) reuse the pool after sync.
    __shared__ u16 pool[24576];
    u8* pool8 = (u8*)pool;
    int mt = blockIdx.x, nt = blockIdx.y, b = blockIdx.z;
    int t = threadIdx.x;
    int wave = t >> 6, lane = t & 63;
    int wm = (wave >> 1) * 64, wn = (wave & 1) * 64;
    int l15 = lane & 15, quad = lane >> 4;
    f32x4 acc[4][4] = {};
    const u16* Ab = A + (size_t)b * asb + (size_t)mt * 128 * lda;
    const u16* Bb = B + (size_t)b * bsb + (size_t)nt * 128 * ldb;
    int swzg = ((lane & 3) ^ ((lane >> 2) & 3) ^ ((lane >> 4) & 3)) * 8;
    int row0 = wave * 16 + (lane >> 2);
    int row1 = 64 + row0;
    const u16* Ap0 = Ab + (size_t)row0 * lda + swzg;
    const u16* Ap1 = Ab + (size_t)row1 * lda + swzg;
    const u16* Bp0 = Bb + (size_t)row0 * ldb + swzg;
    const u16* Bp1 = Bb + (size_t)row1 * ldb + swzg;
    int wo = wave * 512;
    int swzf = (l15 & 3) ^ (l15 >> 2);
    int aoff = (wm + l15) * 32 + ((quad ^ swzf) * 8);
    int boff = (wn + l15) * 32 + ((quad ^ swzf) * 8);
    const int iters = K >> 5;
    // prologue: iter0 -> buf0, iter1 -> buf1 (4 loads each, in order)
    gload16(Ap0, pool + wo);                gload16(Ap1, pool + 2048 + wo);
    gload16(Bp0, pool + 12288 + wo);        gload16(Bp1, pool + 12288 + 2048 + wo);
    gload16(Ap0 + 32, pool + 4096 + wo);    gload16(Ap1 + 32, pool + 4096 + 2048 + wo);
    gload16(Bp0 + 32, pool + 16384 + wo);   gload16(Bp1 + 32, pool + 16384 + 2048 + wo);
    int bs = 0;
    for (int i = 0; i < iters; ++i) {
        if (i + 1 < iters) { ASM_WAITV(4); } else { ASM_WAITV(0); }
        ASM_SBAR();
        const u16* As = pool + bs;
        const u16* Bs = pool + 12288 + bs;
        bf8v af[4], bfr[4];
        #pragma unroll
        for (int ii = 0; ii < 4; ++ii)
            af[ii] = ld_bf8(&As[aoff + ii * 512]);
        #pragma unroll
        for (int j = 0; j < 4; ++j)
            bfr[j] = ld_bf8(&Bs[boff + j * 512]);
        if (i + 2 < iters) {
            int kk = (i + 2) * 32;
            int nb = bs + 8192; if (nb >= 12288) nb -= 12288;
            u16* as = pool + nb; u16* bsp = pool + 12288 + nb;
            gload16(Ap0 + kk, as + wo);        gload16(Ap1 + kk, as + 2048 + wo);
            gload16(Bp0 + kk, bsp + wo);       gload16(Bp1 + kk, bsp + 2048 + wo);
        }
        __builtin_amdgcn_s_setprio(1);
        #pragma unroll
        for (int ii = 0; ii < 4; ++ii)
            #pragma unroll
            for (int j = 0; j < 4; ++j)
                acc[ii][j] = __builtin_amdgcn_mfma_f32_16x16x32_bf16(af[ii], bfr[j], acc[ii][j], 0, 0, 0);
        __builtin_amdgcn_s_setprio(0);
        bs += 4096; if (bs >= 12288) bs -= 12288;
    }
    if (MODE == 0) {
        int nt_sel = nt >> 2, ntl = nt & 3;
        if (nt_sel == 2) {
            // v8: transposed fp8 store via LDS (u32-packed over 4 rows, ~2-way conflicts)
            __syncthreads();
            #pragma unroll
            for (int j = 0; j < 4; ++j) {
                float bv = bias[nt * 128 + wn + j * 16 + l15];
                #pragma unroll
                for (int i = 0; i < 4; ++i) {
                    int col = wn + j * 16 + l15;
                    int row = wm + i * 16 + quad * 4;
                    unsigned int w = __builtin_amdgcn_cvt_pk_fp8_f32(acc[i][j][0] + bv, acc[i][j][1] + bv, 0, false);
                    w = __builtin_amdgcn_cvt_pk_fp8_f32(acc[i][j][2] + bv, acc[i][j][3] + bv, w, true);
                    *reinterpret_cast<unsigned int*>(&pool8[col * 144 + row]) = w;
                }
            }
            __syncthreads();
            u8* Ob = Ov + (size_t)b * osb + (size_t)(ntl * 128) * LL + mt * 128;
            #pragma unroll
            for (int it = 0; it < 4; ++it) {
                int idx = it * 256 + t;
                int row = idx >> 3, ch = (idx & 7) * 16;
                *reinterpret_cast<float4*>(Ob + (size_t)row * LL + ch) =
                    *reinterpret_cast<const float4*>(&pool8[row * 144 + ch]);
            }
        } else {
            // q8/k8: direct global byte stores (16B-coalesced per quad, fire-and-forget)
            u8* Oc = (nt_sel == 0 ? Oq : Ok) + (size_t)b * osb
                     + (size_t)(mt * 128) * CC + ntl * 128 + wn + l15;
            #pragma unroll
            for (int j = 0; j < 4; ++j) {
                float bv = bias[nt * 128 + wn + j * 16 + l15];
                #pragma unroll
                for (int i = 0; i < 4; ++i)
                    #pragma unroll
                    for (int r = 0; r < 4; ++r) {
                        int row = wm + i * 16 + quad * 4 + r;
                        Oc[(size_t)row * CC + j * 16] = f2fp8(acc[i][j][r] + bv);
                    }
            }
        }
    } else {
        // MODE 3: bf16 tile (stride 136 u16) -> residual + f32 transposed store
        __syncthreads();
        #pragma unroll
        for (int j = 0; j < 4; ++j) {
            float bv = bias[nt * 128 + wn + j * 16 + l15];
            #pragma unroll
            for (int i = 0; i < 4; ++i)
                #pragma unroll
                for (int r = 0; r < 4; ++r) {
                    int row = wm + i * 16 + quad * 4 + r;
                    int col = wn + j * 16 + l15;
                    pool[col * 136 + row] = f2bf(acc[i][j][r] + bv);
                }
        }
        __syncthreads();
        const float* xb = xres + ((size_t)b * CC + nt * 128) * LL + mt * 128;
        float* ob = fout + ((size_t)b * CC + nt * 128) * LL + mt * 128;
        #pragma unroll
        for (int it = 0; it < 16; ++it) {
            int idx = it * 256 + t;
            int cl = idx >> 5, ch = (idx & 31) * 4;
            short4 pv = *reinterpret_cast<const short4*>(&pool[cl * 136 + ch]);
            float4 xv = *reinterpret_cast<const float4*>(xb + (size_t)cl * LL + ch);
            float4 ov;
            ov.x = xv.x + bf2f((u16)pv.x);
            ov.y = xv.y + bf2f((u16)pv.y);
            ov.z = xv.z + bf2f((u16)pv.z);
            ov.w = xv.w + bf2f((u16)pv.w);
            *reinterpret_cast<float4*>(ob + (size_t)cl * LL + ch) = ov;
        }
    }
}

// ------- attention S-pass: 1-WAVE blocks, 64x64 tiles, BARRIER-FREE -------
// Each 64-thread block computes S[64x64] for (mt,nt,b): K=512 in 16 BK=32 steps,
// 3 private LDS buffers (4KB each: A 2KB + B 2KB), prefetch distance 2.
// No s_barrier anywhere: global_load_lds completion is the wave's own vmcnt;
// read-before-overwrite is ordered by the lgkmcnt waits before each MFMA.
// Staging swizzle: row R covered by lanes 2R/2R+1, source 16B-chunk
// c16 = (e ^ (R&1) ^ ((R>>2)&1)) (parity invariant under R+=16/32, so the
// fragment-read unswizzle fo is row-uniform per l15).
// Epilogue: P' = exp(acc*scale - 3) -> fp8 direct global byte stores; rowsum
// via 16-lane shuffle reduce + atomicAdd (64 col-blocks contribute per row).
__global__ __launch_bounds__(64) void gemm8s_kernel(const u8* __restrict__ A,
                                                    const u8* __restrict__ B,
                                                    float scale,
                                                    u8* __restrict__ Out8,
                                                    float* __restrict__ rsum) {
    __shared__ u8 pool8[12288];
    int mt = blockIdx.x, nt = blockIdx.y, b = blockIdx.z;
    int lane = threadIdx.x;
    int l15 = lane & 15, quad = lane >> 4;
    f32x4 acc[4][4] = {};
    int R = lane >> 1;
    int c16 = ((lane & 1) ^ (R & 1) ^ ((R >> 2) & 1)) * 16;
    const size_t BLC = (size_t)LL * CC;
    const u8* Ap = A + (size_t)b * BLC + (size_t)(mt * 64 + R) * CC + c16;
    const u8* Bp = B + (size_t)b * BLC + (size_t)(nt * 64 + R) * CC + c16;
    // fragment read: 8 B at row l15 + ii*16, 8B-chunk quad (unswizzled)
    int p = (l15 & 1) ^ ((l15 >> 2) & 1);
    int fo = (((quad >> 1) ^ p) * 16) + (quad & 1) * 8;
    int abase = l15 * 32 + fo;
    // buffer layout: bb + [0,2048) = A rows 0-63, bb + [2048,4096) = B rows 0-63
    #define STGS(ii, bb) do { size_t kk = (size_t)(ii) * 32;               \
        gload16b(Ap + kk,           pool8 + (bb));                         \
        gload16b(Ap + 32 * CC + kk, pool8 + (bb) + 1024);                  \
        gload16b(Bp + kk,           pool8 + (bb) + 2048);                  \
        gload16b(Bp + 32 * CC + kk, pool8 + (bb) + 3072); } while (0)
    const int iters = CC >> 5;   // 16
    STGS(0, 0);
    STGS(1, 4096);
    int bs = 0;
    for (int i = 0; i < iters; ++i) {
        if (i + 1 < iters) { ASM_WAITV(4); } else { ASM_WAITV(0); }
        const u8* As = pool8 + bs;
        const u8* Bs = pool8 + bs + 2048;
        long af[4], bf[4];
        #pragma unroll
        for (int ii = 0; ii < 4; ++ii)
            af[ii] = *reinterpret_cast<const long*>(As + abase + ii * 512);
        #pragma unroll
        for (int j = 0; j < 4; ++j)
            bf[j] = *reinterpret_cast<const long*>(Bs + abase + j * 512);
        if (i + 2 < iters) {
            int nb = bs + 8192; if (nb >= 12288) nb -= 12288;
            STGS(i + 2, nb);
        }
        __builtin_amdgcn_s_setprio(1);
        #pragma unroll
        for (int ii = 0; ii < 4; ++ii)
            #pragma unroll
            for (int j = 0; j < 4; ++j)
                acc[ii][j] = __builtin_amdgcn_mfma_f32_16x16x32_fp8_fp8(af[ii], bf[j], acc[ii][j], 0, 0, 0);
        __builtin_amdgcn_s_setprio(0);
        bs += 4096; if (bs >= 12288) bs -= 12288;
    }
    #undef STGS
    // P' = exp(acc*scale - 3): e4m3-safe (max ~e^2.5=12 << 448).
    u8* Ob = Out8 + (size_t)b * ((size_t)LL * LL) + (size_t)(mt * 64) * LL + nt * 64 + l15;
    float* rbase = rsum + (size_t)b * LL + mt * 64;
    #pragma unroll
    for (int i = 0; i < 4; ++i) {
        #pragma unroll
        for (int r = 0; r < 4; ++r) {
            int row = i * 16 + quad * 4 + r;
            u8* rp = Ob + (size_t)row * LL;
            float part = 0.f;
            #pragma unroll
            for (int j = 0; j < 4; ++j) {
                float v = __expf(acc[i][j][r] * scale - 3.0f);
                part += v;
                rp[j * 16] = f2fp8(v);
            }
            part += __shfl_xor(part, 1, 64);
            part += __shfl_xor(part, 2, 64);
            part += __shfl_xor(part, 4, 64);
            part += __shfl_xor(part, 8, 64);
            if (l15 == 0)
                atomicAdd(rbase + row, part);
        }
    }
}

// ---------------- PV pass: MX-scaled 32x32x64 fp8 GEMM ----------------
// A=P' fp8 [i][j], B=v8 [c][l]; out = acc/rowsum -> bf16 OutH [l][c].
// BK=64, 3 LDS buffers, prefetch distance 2, ONE barrier per K-step (R6 config).
__global__ __launch_bounds__(256) void gemm8_kernel(const u8* __restrict__ A, size_t asb, int lda,
                                                    const u8* __restrict__ B, size_t bsb, int ldb,
                                                    u16* __restrict__ OutH,
                                                    size_t osb, int Nout, int K,
                                                    const float* __restrict__ rsum) {
    __shared__ u8 pool8[49152];
    int mt = blockIdx.x, nt = blockIdx.y, b = blockIdx.z;
    int t = threadIdx.x;
    int wave = t >> 6, lane = t & 63;
    int wm = (wave >> 1) * 64, wn = (wave & 1) * 64;
    int l31 = lane & 31, hsel = lane >> 5;
    f32x16 accm[2][2] = {};
    int R = wave * 32 + (lane >> 1);
    int c16 = ((lane & 1) ^ (R & 1) ^ ((R >> 2) & 1)) * 16;
    const u8* Ap = A + (size_t)b * asb + (size_t)(mt * 128 + R) * lda + c16;
    const u8* Bp = B + (size_t)b * bsb + (size_t)(nt * 128 + R) * ldb + c16;
    int wo = wave * 1024;
    int ra = wm + l31;
    int rb = wn + l31;
    int sa = (ra & 1) ^ ((ra >> 2) & 1);
    int sb = (rb & 1) ^ ((rb >> 2) & 1);
    int a_lo = hsel * 4096 + ra * 32 + sa * 16;
    int a_hi = hsel * 4096 + ra * 32 + 16 - sa * 16;
    int b_lo = hsel * 4096 + rb * 32 + sb * 16;
    int b_hi = hsel * 4096 + rb * 32 + 16 - sb * 16;
    const int iters = K >> 6;
    #define STG2(ii, bsv) do { size_t kk = (size_t)(ii) * 64;              \
        gload16b(Ap + kk,      pool8 + (bsv) + wo);                        \
        gload16b(Ap + kk + 32, pool8 + (bsv) + 4096 + wo);                 \
        gload16b(Bp + kk,      pool8 + 24576 + (bsv) + wo);                \
        gload16b(Bp + kk + 32, pool8 + 24576 + (bsv) + 4096 + wo); } while (0)
    STG2(0, 0);
    STG2(1, 8192);
    int bs = 0;
    for (int i = 0; i < iters; ++i) {
        if (i + 1 < iters) { ASM_WAITV(4); } else { ASM_WAITV(0); }
        ASM_SBAR();
        const u8* As = pool8 + bs;
        const u8* Bs = pool8 + 24576 + bs;
        i32x8 a0 = ld32(As + a_lo, As + a_hi);
        i32x8 a1 = ld32(As + 1024 + a_lo, As + 1024 + a_hi);
        i32x8 b0 = ld32(Bs + b_lo, Bs + b_hi);
        i32x8 b1 = ld32(Bs + 1024 + b_lo, Bs + 1024 + b_hi);
        if (i + 2 < iters) {
            int nb = bs + 16384; if (nb >= 24576) nb -= 24576;
            STG2(i + 2, nb);
        }
        __builtin_amdgcn_s_setprio(1);
        accm[0][0] = MFMA_SC(a0, b0, accm[0][0]);
        accm[0][1] = MFMA_SC(a0, b1, accm[0][1]);
        accm[1][0] = MFMA_SC(a1, b0, accm[1][0]);
        accm[1][1] = MFMA_SC(a1, b1, accm[1][1]);
        __builtin_amdgcn_s_setprio(0);
        bs += 8192; if (bs >= 24576) bs -= 24576;
    }
    #undef STG2
    // normalize rows by 1/rowsum (float4 per reg-group), bf16 out via LDS
    __syncthreads();
    u16* poolh = (u16*)pool8;
    const float* rbase2 = rsum + (size_t)b * LL + mt * 128;
    #pragma unroll
    for (int i = 0; i < 2; ++i)
        #pragma unroll
        for (int rg = 0; rg < 4; ++rg) {
            int row0 = wm + i * 32 + 8 * rg + 4 * hsel;
            float4 rv = *reinterpret_cast<const float4*>(rbase2 + row0);
            float iv[4] = {1.f / rv.x, 1.f / rv.y, 1.f / rv.z, 1.f / rv.w};
            #pragma unroll
            for (int rr = 0; rr < 4; ++rr) {
                int reg = rg * 4 + rr;
                int row = row0 + rr;
                poolh[row * 136 + wn + l31]      = f2bf(accm[i][0][reg] * iv[rr]);
                poolh[row * 136 + wn + 32 + l31] = f2bf(accm[i][1][reg] * iv[rr]);
            }
        }
    __syncthreads();
    u16* Ob = OutH + (size_t)b * osb + (size_t)(mt * 128) * Nout + nt * 128;
    #pragma unroll
    for (int it = 0; it < 8; ++it) {
        int idx = it * 256 + t;
        int row = idx >> 4, ch = (idx & 15) * 8;
        s16x8 val = *reinterpret_cast<const s16x8*>(&poolh[row * 136 + ch]);
        *reinterpret_cast<s16x8*>(Ob + (size_t)row * Nout + ch) = val;
    }
}

extern "C" void kernel_launch(void* const* d_in, const int* in_sizes, int n_in,
                              void* d_out, int out_size, void* d_ws, size_t ws_size,
                              hipStream_t stream) {
    const float* x   = (const float*)d_in[0];
    const float* gsc = (const float*)d_in[1];
    const float* gbi = (const float*)d_in[2];
    const float* wq  = (const float*)d_in[3];
    const float* bq  = (const float*)d_in[4];
    const float* wk  = (const float*)d_in[5];
    const float* bk  = (const float*)d_in[6];
    const float* wv  = (const float*)d_in[7];
    const float* bv  = (const float*)d_in[8];
    const float* wp  = (const float*)d_in[9];
    const float* bp  = (const float*)d_in[10];
    float* out = (float*)d_out;

    char* ws = (char*)d_ws;
    const size_t SZ   = (size_t)BB * LL * CC * 2;     // 16 MiB bf16 [b][l][c] (hT / h2T)
    const size_t QSZ  = (size_t)BB * LL * CC;         // 8 MiB fp8 per q/k/v buffer
    const size_t WQSZ = (size_t)4 * CC * CC * 2;      // 2 MiB bf16 weights
    const size_t RSZ  = (size_t)BB * LL * 4;          // 64 KiB f32 rowsums
    u16* bufA = (u16*)(ws);                           // hT, then h2T
    u8*  q8   = (u8*)(ws + SZ);
    u8*  k8   = (u8*)(ws + SZ + QSZ);
    u8*  v8   = (u8*)(ws + SZ + 2 * QSZ);             // [b][c][l] fp8
    u16* wbf  = (u16*)(ws + SZ + 3 * QSZ);
    float2* stats = (float2*)(ws + SZ + 3 * QSZ + WQSZ);
    float* bcat   = (float*)(ws + SZ + 3 * QSZ + WQSZ + 4096);
    float* rowsum = (float*)(ws + SZ + 3 * QSZ + WQSZ + 4096 + 8192);
    u8* S8 = (u8*)(ws + SZ + 3 * QSZ + WQSZ + 4096 + 8192 + RSZ);   // 64 MiB fp8 scores
    const float scale = 0.044194173824159216f;        // 512^-0.5
    const size_t BLC = (size_t)LL * CC;

    wconv_kernel<<<dim3(256, 4), 256, 0, stream>>>(wq, wk, wv, wp, wbf);
    biascat_kernel<<<dim3(64), 256, 0, stream>>>(bq, bk, bv, bcat, rowsum);
    gn_stats_kernel<<<dim3(NG, BB), 256, 0, stream>>>(x, stats);
    gn_norm_t_kernel<<<dim3(64, 8, BB), 256, 0, stream>>>(x, stats, gsc, gbi, bufA);
    // fused QKV (bf16 compute, fp8 outputs): nt 0-3 -> q8, 4-7 -> k8, 8-11 -> v8^T
    gemm_kernel<0><<<dim3(32, 12, BB), 256, 0, stream>>>(bufA, BLC, CC, wbf, 0, CC, bcat,
                                                         q8, k8, v8, BLC, nullptr, nullptr, CC);
    // attention: P' = exp(QK^T*scale - 3) fp8 + rowsums (1-wave 64x64 blocks);
    // O = (P' V) / rowsum
    gemm8s_kernel<<<dim3(64, 64, BB), 64, 0, stream>>>(q8, k8, scale, S8, rowsum);
    gemm8_kernel<<<dim3(32, 4, BB), 256, 0, stream>>>(S8, (size_t)LL * LL, LL, v8, BLC, LL,
                                                      bufA, BLC, CC, LL, rowsum);
    // proj + residual + transposed f32 store
    gemm_kernel<3><<<dim3(32, 4, BB), 256, 0, stream>>>(bufA, BLC, CC, wbf + 3 * CC * CC, 0, CC,
                                                        bp, nullptr, nullptr, nullptr, 0, x, out, CC);
}

// Round 9
// 299.871 us; speedup vs baseline: 1.1839x; 1.1839x over previous
//
#include <hip/hip_runtime.h>
#include <math.h>

// Shapes (fixed by the problem): b=4, c=512, l=4096, 32 groups.
// Inputs/outputs are float32; internal path: bf16 MFMA for QKV/proj,
// attention S-pass: non-scaled fp8 16x16x32, serial 2-tile supertile,
// attention PV-pass: MX-scaled fp8 32x32x64 (throughput-bound, 2x rate wins).
#define BB 4
#define CC 512
#define LL 4096
#define NG 32
#define CPG 16
#define EPSV 1e-6f

typedef short s16x8 __attribute__((ext_vector_type(8)));
typedef __bf16 bf8v __attribute__((ext_vector_type(8)));
typedef float f32x4 __attribute__((ext_vector_type(4)));
typedef float f32x16 __attribute__((ext_vector_type(16)));
typedef int i32x4 __attribute__((ext_vector_type(4)));
typedef int i32x8 __attribute__((ext_vector_type(8)));
typedef unsigned short u16;
typedef unsigned char u8;

typedef const __attribute__((address_space(1))) void g1_void;
typedef __attribute__((address_space(3))) void l3_void;

// raw barrier / waitcnt (memory clobber = compiler reorder fence, no vmcnt drain)
#define ASM_SBAR() asm volatile("s_barrier" ::: "memory")
#define ASM_WAITV(N) asm volatile("s_waitcnt vmcnt(" #N ")" ::: "memory")

static __device__ __forceinline__ float bf2f(u16 h) {
    unsigned int u = ((unsigned int)h) << 16;
    union { unsigned int u; float f; } c; c.u = u; return c.f;
}
static __device__ __forceinline__ u16 f2bf(float f) {
    union { float f; unsigned int u; } c; c.f = f;
    unsigned int lsb = (c.u >> 16) & 1u;
    c.u += 0x7fffu + lsb;           // round-to-nearest-even
    return (u16)(c.u >> 16);
}
static __device__ __forceinline__ u8 f2fp8(float f) {
    int v = __builtin_amdgcn_cvt_pk_fp8_f32(f, f, 0, false);  // OCP e4m3fn, saturating
    return (u8)(v & 0xff);
}
static __device__ __forceinline__ bf8v ld_bf8(const u16* p) {
    return *reinterpret_cast<const bf8v*>(p);
}
// assemble a 32-byte fp8 operand (v8i32) from two 16-B LDS chunks (global k order)
static __device__ __forceinline__ i32x8 ld32(const u8* plo, const u8* phi) {
    i32x4 lo = *reinterpret_cast<const i32x4*>(plo);
    i32x4 hi = *reinterpret_cast<const i32x4*>(phi);
    return __builtin_shufflevector(lo, hi, 0, 1, 2, 3, 4, 5, 6, 7);
}
// MX-scaled fp8 MFMA with unit scales (e8m0 0x7f = 2^0): runs at the 2x fp8 rate
#define MFMA_SC(a, b, c) \
    __builtin_amdgcn_mfma_scale_f32_32x32x64_f8f6f4(a, b, c, 0, 0, 0, 0x7f, 0, 0x7f)

// async global->LDS; HW writes lds_base + lane*16 (wave-uniform base required)
static __device__ __forceinline__ void gload16(const u16* g, u16* l) {
    __builtin_amdgcn_global_load_lds((g1_void*)g, (l3_void*)l, 16, 0, 0);
}
static __device__ __forceinline__ void gload16b(const u8* g, u8* l) {
    __builtin_amdgcn_global_load_lds((g1_void*)g, (l3_void*)l, 16, 0, 0);
}

// ---------------- weight convert: four 512x512 f32 -> bf16 (rows: q,k,v,p) ----------------
__global__ __launch_bounds__(256) void wconv_kernel(const float* __restrict__ w0,
                                                    const float* __restrict__ w1,
                                                    const float* __restrict__ w2,
                                                    const float* __restrict__ w3,
                                                    u16* __restrict__ wbf) {
    int i = blockIdx.x * 256 + threadIdx.x;      // 0..65535 float4 chunks
    int wsel = blockIdx.y;
    const float* src = (wsel == 0) ? w0 : (wsel == 1) ? w1 : (wsel == 2) ? w2 : w3;
    float4 v = reinterpret_cast<const float4*>(src)[i];
    ushort4 o;
    o.x = f2bf(v.x); o.y = f2bf(v.y); o.z = f2bf(v.z); o.w = f2bf(v.w);
    reinterpret_cast<ushort4*>(wbf + (size_t)wsel * CC * CC)[i] = o;
}

// -------- concat q/k/v biases into one f32[1536] + zero the rowsum buffer --------
__global__ __launch_bounds__(256) void biascat_kernel(const float* __restrict__ bq,
                                                      const float* __restrict__ bk,
                                                      const float* __restrict__ bv,
                                                      float* __restrict__ bcat,
                                                      float* __restrict__ rowsum) {
    int i = blockIdx.x * 256 + threadIdx.x;
    if (i < 3 * CC) {
        float v = (i < CC) ? bq[i] : (i < 2 * CC ? bk[i - CC] : bv[i - 2 * CC]);
        bcat[i] = v;
    }
    if (i < BB * LL) rowsum[i] = 0.f;
}

// ---------------- GroupNorm stats: one block per (group, batch) ----------------
__global__ __launch_bounds__(256) void gn_stats_kernel(const float* __restrict__ x,
                                                       float2* __restrict__ stats) {
    int g = blockIdx.x, b = blockIdx.y, t = threadIdx.x;
    const float4* xp = reinterpret_cast<const float4*>(x + ((size_t)b * CC + (size_t)g * CPG) * LL);
    float s = 0.f, ss = 0.f;
    for (int it = 0; it < 64; ++it) {
        float4 v = xp[it * 256 + t];
        s += v.x + v.y + v.z + v.w;
        ss += v.x * v.x + v.y * v.y + v.z * v.z + v.w * v.w;
    }
    #pragma unroll
    for (int off = 32; off; off >>= 1) { s += __shfl_xor(s, off, 64); ss += __shfl_xor(ss, off, 64); }
    __shared__ float rs[4], rss[4];
    int wave = t >> 6, lane = t & 63;
    if (lane == 0) { rs[wave] = s; rss[wave] = ss; }
    __syncthreads();
    if (t == 0) {
        float S = rs[0] + rs[1] + rs[2] + rs[3];
        float SS = rss[0] + rss[1] + rss[2] + rss[3];
        float mean = S * (1.f / 65536.f);
        float var = SS * (1.f / 65536.f) - mean * mean;
        var = fmaxf(var, 0.f);
        stats[b * NG + g] = make_float2(mean, rsqrtf(var + EPSV));
    }
}

// -------- GroupNorm normalize + transpose: x[b][c][l] f32 -> hT[b][l][c] bf16 --------
__global__ __launch_bounds__(256) void gn_norm_t_kernel(const float* __restrict__ x,
                                                        const float2* __restrict__ stats,
                                                        const float* __restrict__ gsc,
                                                        const float* __restrict__ gbi,
                                                        u16* __restrict__ hT) {
    int lt = blockIdx.x, ct = blockIdx.y, b = blockIdx.z;
    __shared__ u16 tile[64][72];
    int t = threadIdx.x;
    int cl0 = t >> 4, c4 = (t & 15) * 4;
    #pragma unroll
    for (int p = 0; p < 4; ++p) {
        int cl = p * 16 + cl0;
        int cg = ct * 64 + cl;
        float2 st = stats[b * NG + (cg >> 4)];
        float sc = gsc[cg] * st.y;
        float bi = gbi[cg];
        float4 v = *reinterpret_cast<const float4*>(x + ((size_t)b * CC + cg) * LL + lt * 64 + c4);
        tile[cl][c4 + 0] = f2bf((v.x - st.x) * sc + bi);
        tile[cl][c4 + 1] = f2bf((v.y - st.x) * sc + bi);
        tile[cl][c4 + 2] = f2bf((v.z - st.x) * sc + bi);
        tile[cl][c4 + 3] = f2bf((v.w - st.x) * sc + bi);
    }
    __syncthreads();
    int r = t >> 3, c8 = (t & 7) * 8;
    #pragma unroll
    for (int p = 0; p < 2; ++p) {
        int ll = p * 32 + r;
        s16x8 ov;
        #pragma unroll
        for (int j = 0; j < 8; ++j) ov[j] = (short)tile[c8 + j][ll];
        u16* hp = hT + ((size_t)b * LL + lt * 64 + ll) * CC + ct * 64 + c8;
        *reinterpret_cast<s16x8*>(hp) = ov;
    }
}

// ---------------- bf16 GEMM: Out = A * B^T + bias ----------------
// MODE 0: fused QKV, fp8 outputs. nt/4==0 -> q8 [l][c], ==1 -> k8 [l][c],
//         ==2 -> v8 stored TRANSPOSED [c][l].
// MODE 3: proj: + bias, TRANSPOSED f32 store with residual: fout = xres + val.
// K-loop: 3 LDS buffers, prefetch distance 2 -> ONE barrier per K-step.
template <int MODE>
__global__ __launch_bounds__(256) void gemm_kernel(const u16* __restrict__ A, size_t asb, int lda,
                                                   const u16* __restrict__ B, size_t bsb, int ldb,
                                                   const float* __restrict__ bias,
                                                   u8* __restrict__ Oq, u8* __restrict__ Ok,
                                                   u8* __restrict__ Ov, size_t osb,
                                                   const float* __restrict__ xres,
                                                   float* __restrict__ fout, int K) {
    // staging 3 x (A 8KB @ b*4096 u16, B 8KB @ 12288+b*4096 u16) = 48 KB;
    // epilogues (fp8 tile 18432 B / bf16 tile 34816 B) reuse the pool after sync.
    __shared__ u16 pool[24576];
    u8* pool8 = (u8*)pool;
    int mt = blockIdx.x, nt = blockIdx.y, b = blockIdx.z;
    int t = threadIdx.x;
    int wave = t >> 6, lane = t & 63;
    int wm = (wave >> 1) * 64, wn = (wave & 1) * 64;
    int l15 = lane & 15, quad = lane >> 4;
    f32x4 acc[4][4] = {};
    const u16* Ab = A + (size_t)b * asb + (size_t)mt * 128 * lda;
    const u16* Bb = B + (size_t)b * bsb + (size_t)nt * 128 * ldb;
    int swzg = ((lane & 3) ^ ((lane >> 2) & 3) ^ ((lane >> 4) & 3)) * 8;
    int row0 = wave * 16 + (lane >> 2);
    int row1 = 64 + row0;
    const u16* Ap0 = Ab + (size_t)row0 * lda + swzg;
    const u16* Ap1 = Ab + (size_t)row1 * lda + swzg;
    const u16* Bp0 = Bb + (size_t)row0 * ldb + swzg;
    const u16* Bp1 = Bb + (size_t)row1 * ldb + swzg;
    int wo = wave * 512;
    int swzf = (l15 & 3) ^ (l15 >> 2);
    int aoff = (wm + l15) * 32 + ((quad ^ swzf) * 8);
    int boff = (wn + l15) * 32 + ((quad ^ swzf) * 8);
    const int iters = K >> 5;
    // prologue: iter0 -> buf0, iter1 -> buf1 (4 loads each, in order)
    gload16(Ap0, pool + wo);                gload16(Ap1, pool + 2048 + wo);
    gload16(Bp0, pool + 12288 + wo);        gload16(Bp1, pool + 12288 + 2048 + wo);
    gload16(Ap0 + 32, pool + 4096 + wo);    gload16(Ap1 + 32, pool + 4096 + 2048 + wo);
    gload16(Bp0 + 32, pool + 16384 + wo);   gload16(Bp1 + 32, pool + 16384 + 2048 + wo);
    int bs = 0;
    for (int i = 0; i < iters; ++i) {
        if (i + 1 < iters) { ASM_WAITV(4); } else { ASM_WAITV(0); }
        ASM_SBAR();
        const u16* As = pool + bs;
        const u16* Bs = pool + 12288 + bs;
        bf8v af[4], bfr[4];
        #pragma unroll
        for (int ii = 0; ii < 4; ++ii)
            af[ii] = ld_bf8(&As[aoff + ii * 512]);
        #pragma unroll
        for (int j = 0; j < 4; ++j)
            bfr[j] = ld_bf8(&Bs[boff + j * 512]);
        if (i + 2 < iters) {
            int kk = (i + 2) * 32;
            int nb = bs + 8192; if (nb >= 12288) nb -= 12288;
            u16* as = pool + nb; u16* bsp = pool + 12288 + nb;
            gload16(Ap0 + kk, as + wo);        gload16(Ap1 + kk, as + 2048 + wo);
            gload16(Bp0 + kk, bsp + wo);       gload16(Bp1 + kk, bsp + 2048 + wo);
        }
        __builtin_amdgcn_s_setprio(1);
        #pragma unroll
        for (int ii = 0; ii < 4; ++ii)
            #pragma unroll
            for (int j = 0; j < 4; ++j)
                acc[ii][j] = __builtin_amdgcn_mfma_f32_16x16x32_bf16(af[ii], bfr[j], acc[ii][j], 0, 0, 0);
        __builtin_amdgcn_s_setprio(0);
        bs += 4096; if (bs >= 12288) bs -= 12288;
    }
    if (MODE == 0) {
        int nt_sel = nt >> 2, ntl = nt & 3;
        if (nt_sel == 2) {
            // v8: transposed fp8 store via LDS (u32-packed over 4 rows, ~2-way conflicts)
            __syncthreads();
            #pragma unroll
            for (int j = 0; j < 4; ++j) {
                float bv = bias[nt * 128 + wn + j * 16 + l15];
                #pragma unroll
                for (int i = 0; i < 4; ++i) {
                    int col = wn + j * 16 + l15;
                    int row = wm + i * 16 + quad * 4;
                    unsigned int w = __builtin_amdgcn_cvt_pk_fp8_f32(acc[i][j][0] + bv, acc[i][j][1] + bv, 0, false);
                    w = __builtin_amdgcn_cvt_pk_fp8_f32(acc[i][j][2] + bv, acc[i][j][3] + bv, w, true);
                    *reinterpret_cast<unsigned int*>(&pool8[col * 144 + row]) = w;
                }
            }
            __syncthreads();
            u8* Ob = Ov + (size_t)b * osb + (size_t)(ntl * 128) * LL + mt * 128;
            #pragma unroll
            for (int it = 0; it < 4; ++it) {
                int idx = it * 256 + t;
                int row = idx >> 3, ch = (idx & 7) * 16;
                *reinterpret_cast<float4*>(Ob + (size_t)row * LL + ch) =
                    *reinterpret_cast<const float4*>(&pool8[row * 144 + ch]);
            }
        } else {
            // q8/k8: direct global byte stores (16B-coalesced per quad, fire-and-forget)
            u8* Oc = (nt_sel == 0 ? Oq : Ok) + (size_t)b * osb
                     + (size_t)(mt * 128) * CC + ntl * 128 + wn + l15;
            #pragma unroll
            for (int j = 0; j < 4; ++j) {
                float bv = bias[nt * 128 + wn + j * 16 + l15];
                #pragma unroll
                for (int i = 0; i < 4; ++i)
                    #pragma unroll
                    for (int r = 0; r < 4; ++r) {
                        int row = wm + i * 16 + quad * 4 + r;
                        Oc[(size_t)row * CC + j * 16] = f2fp8(acc[i][j][r] + bv);
                    }
            }
        }
    } else {
        // MODE 3: bf16 tile (stride 136 u16) -> residual + f32 transposed store
        __syncthreads();
        #pragma unroll
        for (int j = 0; j < 4; ++j) {
            float bv = bias[nt * 128 + wn + j * 16 + l15];
            #pragma unroll
            for (int i = 0; i < 4; ++i)
                #pragma unroll
                for (int r = 0; r < 4; ++r) {
                    int row = wm + i * 16 + quad * 4 + r;
                    int col = wn + j * 16 + l15;
                    pool[col * 136 + row] = f2bf(acc[i][j][r] + bv);
                }
        }
        __syncthreads();
        const float* xb = xres + ((size_t)b * CC + nt * 128) * LL + mt * 128;
        float* ob = fout + ((size_t)b * CC + nt * 128) * LL + mt * 128;
        #pragma unroll
        for (int it = 0; it < 16; ++it) {
            int idx = it * 256 + t;
            int cl = idx >> 5, ch = (idx & 31) * 4;
            short4 pv = *reinterpret_cast<const short4*>(&pool[cl * 136 + ch]);
            float4 xv = *reinterpret_cast<const float4*>(xb + (size_t)cl * LL + ch);
            float4 ov;
            ov.x = xv.x + bf2f((u16)pv.x);
            ov.y = xv.y + bf2f((u16)pv.y);
            ov.z = xv.z + bf2f((u16)pv.z);
            ov.w = xv.w + bf2f((u16)pv.w);
            *reinterpret_cast<float4*>(ob + (size_t)cl * LL + ch) = ov;
        }
    }
}

// ---------------- fp8 GEMM (attention S and PV passes) ----------------
// MODE 1 (S, K=512, latency-bound): non-scaled 16x16x32 fp8, SERIAL 2-TILE
//   SUPERTILE: each block computes (mt, nt) then (mt, nt+16) as two sequential
//   BK=64 K-loops sharing one continuous 3-buffer rotation. During subtile 0's
//   iters 6-7 the i+2 prefetch cadence rolls into subtile 1's tiles 0-1, so
//   subtile 0's epilogue (exp + fp8 stores + rowsum atomics) runs entirely
//   under subtile 1's in-flight prologue loads. WAITV(4) throughout (2 tiles
//   in flight at every iter top); WAITV(0) only at the true end. acc reused
//   across subtiles (#pragma unroll 1 keeps one body -> no regalloc doubling).
// MODE 2 (PV, K=4096, throughput-bound): MX-scaled 32x32x64 (unit scales, 2x
//   fp8 rate), BK=64, 3 buffers, distance 2 (R6 config, unchanged).
// Staging 16-B chunk swizzle c16 = (e ^ (R&1) ^ ((R>>2)&1)) breaks 4-way frag
// conflicts; MODE1 undoes it via quad-swizzled 8B frag reads, MODE2 per row at
// ld32 time. 32x32 C/D layout: col=lane&31, row=(reg&3)+8*(reg>>2)+4*(lane>>5).
template <int MODE>
__global__ __launch_bounds__(256) void gemm8_kernel(const u8* __restrict__ A, size_t asb, int lda,
                                                    const u8* __restrict__ B, size_t bsb, int ldb,
                                                    float scale,
                                                    u8* __restrict__ Out8, u16* __restrict__ OutH,
                                                    size_t osb, int Nout, int K,
                                                    float* __restrict__ rsum) {
    // staging: 3 x (A 8KB @ b*8192, B 8KB @ 24576 + b*8192) = 48 KB;
    // MODE 2 epilogue bf16 tile 34816 B reuses the pool after sync.
    __shared__ u8 pool8[49152];
    int mt = blockIdx.x, nt = blockIdx.y, b = blockIdx.z;
    int t = threadIdx.x;
    int wave = t >> 6, lane = t & 63;
    int wm = (wave >> 1) * 64, wn = (wave & 1) * 64;
    int l15 = lane & 15, quad = lane >> 4;
    int l31 = lane & 31, hsel = lane >> 5;
    int R = wave * 32 + (lane >> 1);
    int c16 = ((lane & 1) ^ (R & 1) ^ ((R >> 2) & 1)) * 16;
    const u8* Ap = A + (size_t)b * asb + (size_t)(mt * 128 + R) * lda + c16;
    const u8* Bp = B + (size_t)b * bsb + (size_t)(nt * 128 + R) * ldb + c16;
    int wo = wave * 1024;
    if (MODE == 1) {
        f32x4 acc16[4][4] = {};
        // fragment reads: 8 B at row base+l15, 8B-chunk quad (swizzled)
        int p = (l15 & 1) ^ ((l15 >> 2) & 1);
        int fo = (((quad >> 1) ^ p) * 16) + (quad & 1) * 8;
        int abase = (wm + l15) * 32 + fo;
        int bbase = (wn + l15) * 32 + fo;
        const int iters = K >> 6;   // 8 (BK=64)
        const u8* Bp2 = Bp + (size_t)2048 * ldb;   // subtile 1 = columns (nt+16)*128
        #define STG1(tt, bsv, BPTR) do { size_t kk = (size_t)(tt) * 64;        \
            gload16b(Ap + kk,        pool8 + (bsv) + wo);                      \
            gload16b(Ap + kk + 32,   pool8 + (bsv) + 4096 + wo);               \
            gload16b(BPTR + kk,      pool8 + 24576 + (bsv) + wo);              \
            gload16b(BPTR + kk + 32, pool8 + 24576 + (bsv) + 4096 + wo); } while (0)
        STG1(0, 0, Bp);
        STG1(1, 8192, Bp);
        int bs = 0;
        #pragma unroll 1
        for (int s = 0; s < 2; ++s) {
            const u8* Bcur = s ? Bp2 : Bp;
            #pragma unroll 1
            for (int i = 0; i < iters; ++i) {
                if (s == 1 && i + 1 >= iters) { ASM_WAITV(0); } else { ASM_WAITV(4); }
                ASM_SBAR();
                const u8* As = pool8 + bs;
                const u8* Bs = pool8 + 24576 + bs;
                long af0[4], bf0[4], af1[4], bf1[4];
                #pragma unroll
                for (int ii = 0; ii < 4; ++ii) {
                    af0[ii] = *reinterpret_cast<const long*>(As + abase + ii * 512);
                    af1[ii] = *reinterpret_cast<const long*>(As + 4096 + abase + ii * 512);
                }
                #pragma unroll
                for (int j = 0; j < 4; ++j) {
                    bf0[j] = *reinterpret_cast<const long*>(Bs + bbase + j * 512);
                    bf1[j] = *reinterpret_cast<const long*>(Bs + 4096 + bbase + j * 512);
                }
                int nb = bs + 16384; if (nb >= 24576) nb -= 24576;
                if (i + 2 < iters)      STG1(i + 2, nb, Bcur);
                else if (s == 0)        STG1(i + 2 - iters, nb, Bp2);
                __builtin_amdgcn_s_setprio(1);
                #pragma unroll
                for (int ii = 0; ii < 4; ++ii)
                    #pragma unroll
                    for (int j = 0; j < 4; ++j)
                        acc16[ii][j] = __builtin_amdgcn_mfma_f32_16x16x32_fp8_fp8(af0[ii], bf0[j], acc16[ii][j], 0, 0, 0);
                #pragma unroll
                for (int ii = 0; ii < 4; ++ii)
                    #pragma unroll
                    for (int j = 0; j < 4; ++j)
                        acc16[ii][j] = __builtin_amdgcn_mfma_f32_16x16x32_fp8_fp8(af1[ii], bf1[j], acc16[ii][j], 0, 0, 0);
                __builtin_amdgcn_s_setprio(0);
                bs += 8192; if (bs >= 24576) bs -= 24576;
            }
            // epilogue subtile s: P' = exp(acc*scale - 3), e4m3-safe (max ~e^2.5=12).
            // Direct global byte stores; rowsum via 16-lane shuffle reduce + atomicAdd.
            // Runs while subtile 1's prologue loads (issued at s0 iters 6-7) fly.
            u8* Ob = Out8 + (size_t)b * osb + (size_t)(mt * 128) * Nout
                     + nt * 128 + s * 2048 + wn + l15;
            #pragma unroll
            for (int i = 0; i < 4; ++i) {
                #pragma unroll
                for (int r = 0; r < 4; ++r) {
                    int row = wm + i * 16 + quad * 4 + r;
                    u8* rp = Ob + (size_t)row * Nout;
                    float part = 0.f;
                    #pragma unroll
                    for (int j = 0; j < 4; ++j) {
                        float v = __expf(acc16[i][j][r] * scale - 3.0f);
                        part += v;
                        rp[j * 16] = f2fp8(v);
                    }
                    part += __shfl_xor(part, 1, 64);
                    part += __shfl_xor(part, 2, 64);
                    part += __shfl_xor(part, 4, 64);
                    part += __shfl_xor(part, 8, 64);
                    if (l15 == 0)
                        atomicAdd(rsum + (size_t)b * LL + mt * 128 + row, part);
                }
            }
            if (s == 0) {
                #pragma unroll
                for (int ii = 0; ii < 4; ++ii)
                    #pragma unroll
                    for (int j = 0; j < 4; ++j)
                        acc16[ii][j] = (f32x4){};
            }
        }
        #undef STG1
    } else {
        // ---- MODE 2: BK=64, 3 buffers, prefetch distance 2 (R6, unchanged) ----
        f32x16 accm[2][2] = {};
        int ra = wm + l31;
        int rb = wn + l31;
        int sa = (ra & 1) ^ ((ra >> 2) & 1);
        int sb = (rb & 1) ^ ((rb >> 2) & 1);
        int a_lo = hsel * 4096 + ra * 32 + sa * 16;
        int a_hi = hsel * 4096 + ra * 32 + 16 - sa * 16;
        int b_lo = hsel * 4096 + rb * 32 + sb * 16;
        int b_hi = hsel * 4096 + rb * 32 + 16 - sb * 16;
        const int iters = K >> 6;
        #define STG2(ii, bsv) do { size_t kk = (size_t)(ii) * 64;              \
            gload16b(Ap + kk,      pool8 + (bsv) + wo);                        \
            gload16b(Ap + kk + 32, pool8 + (bsv) + 4096 + wo);                 \
            gload16b(Bp + kk,      pool8 + 24576 + (bsv) + wo);                \
            gload16b(Bp + kk + 32, pool8 + 24576 + (bsv) + 4096 + wo); } while (0)
        STG2(0, 0);
        STG2(1, 8192);
        int bs = 0;
        for (int i = 0; i < iters; ++i) {
            if (i + 1 < iters) { ASM_WAITV(4); } else { ASM_WAITV(0); }
            ASM_SBAR();
            const u8* As = pool8 + bs;
            const u8* Bs = pool8 + 24576 + bs;
            i32x8 a0 = ld32(As + a_lo, As + a_hi);
            i32x8 a1 = ld32(As + 1024 + a_lo, As + 1024 + a_hi);
            i32x8 b0 = ld32(Bs + b_lo, Bs + b_hi);
            i32x8 b1 = ld32(Bs + 1024 + b_lo, Bs + 1024 + b_hi);
            if (i + 2 < iters) {
                int nb = bs + 16384; if (nb >= 24576) nb -= 24576;
                STG2(i + 2, nb);
            }
            __builtin_amdgcn_s_setprio(1);
            accm[0][0] = MFMA_SC(a0, b0, accm[0][0]);
            accm[0][1] = MFMA_SC(a0, b1, accm[0][1]);
            accm[1][0] = MFMA_SC(a1, b0, accm[1][0]);
            accm[1][1] = MFMA_SC(a1, b1, accm[1][1]);
            __builtin_amdgcn_s_setprio(0);
            bs += 8192; if (bs >= 24576) bs -= 24576;
        }
        #undef STG2
        // normalize rows by 1/rowsum (float4 per reg-group), bf16 out via LDS
        __syncthreads();
        u16* poolh = (u16*)pool8;
        const float* rbase2 = rsum + (size_t)b * LL + mt * 128;
        #pragma unroll
        for (int i = 0; i < 2; ++i)
            #pragma unroll
            for (int rg = 0; rg < 4; ++rg) {
                int row0 = wm + i * 32 + 8 * rg + 4 * hsel;
                float4 rv = *reinterpret_cast<const float4*>(rbase2 + row0);
                float iv[4] = {1.f / rv.x, 1.f / rv.y, 1.f / rv.z, 1.f / rv.w};
                #pragma unroll
                for (int rr = 0; rr < 4; ++rr) {
                    int reg = rg * 4 + rr;
                    int row = row0 + rr;
                    poolh[row * 136 + wn + l31]      = f2bf(accm[i][0][reg] * iv[rr]);
                    poolh[row * 136 + wn + 32 + l31] = f2bf(accm[i][1][reg] * iv[rr]);
                }
            }
        __syncthreads();
        u16* Ob = OutH + (size_t)b * osb + (size_t)(mt * 128) * Nout + nt * 128;
        #pragma unroll
        for (int it = 0; it < 8; ++it) {
            int idx = it * 256 + t;
            int row = idx >> 4, ch = (idx & 15) * 8;
            s16x8 val = *reinterpret_cast<const s16x8*>(&poolh[row * 136 + ch]);
            *reinterpret_cast<s16x8*>(Ob + (size_t)row * Nout + ch) = val;
        }
    }
}

extern "C" void kernel_launch(void* const* d_in, const int* in_sizes, int n_in,
                              void* d_out, int out_size, void* d_ws, size_t ws_size,
                              hipStream_t stream) {
    const float* x   = (const float*)d_in[0];
    const float* gsc = (const float*)d_in[1];
    const float* gbi = (const float*)d_in[2];
    const float* wq  = (const float*)d_in[3];
    const float* bq  = (const float*)d_in[4];
    const float* wk  = (const float*)d_in[5];
    const float* bk  = (const float*)d_in[6];
    const float* wv  = (const float*)d_in[7];
    const float* bv  = (const float*)d_in[8];
    const float* wp  = (const float*)d_in[9];
    const float* bp  = (const float*)d_in[10];
    float* out = (float*)d_out;

    char* ws = (char*)d_ws;
    const size_t SZ   = (size_t)BB * LL * CC * 2;     // 16 MiB bf16 [b][l][c] (hT / h2T)
    const size_t QSZ  = (size_t)BB * LL * CC;         // 8 MiB fp8 per q/k/v buffer
    const size_t WQSZ = (size_t)4 * CC * CC * 2;      // 2 MiB bf16 weights
    const size_t RSZ  = (size_t)BB * LL * 4;          // 64 KiB f32 rowsums
    u16* bufA = (u16*)(ws);                           // hT, then h2T
    u8*  q8   = (u8*)(ws + SZ);
    u8*  k8   = (u8*)(ws + SZ + QSZ);
    u8*  v8   = (u8*)(ws + SZ + 2 * QSZ);             // [b][c][l] fp8
    u16* wbf  = (u16*)(ws + SZ + 3 * QSZ);
    float2* stats = (float2*)(ws + SZ + 3 * QSZ + WQSZ);
    float* bcat   = (float*)(ws + SZ + 3 * QSZ + WQSZ + 4096);
    float* rowsum = (float*)(ws + SZ + 3 * QSZ + WQSZ + 4096 + 8192);
    u8* S8 = (u8*)(ws + SZ + 3 * QSZ + WQSZ + 4096 + 8192 + RSZ);   // 64 MiB fp8 scores
    const float scale = 0.044194173824159216f;        // 512^-0.5
    const size_t BLC = (size_t)LL * CC;

    wconv_kernel<<<dim3(256, 4), 256, 0, stream>>>(wq, wk, wv, wp, wbf);
    biascat_kernel<<<dim3(64), 256, 0, stream>>>(bq, bk, bv, bcat, rowsum);
    gn_stats_kernel<<<dim3(NG, BB), 256, 0, stream>>>(x, stats);
    gn_norm_t_kernel<<<dim3(64, 8, BB), 256, 0, stream>>>(x, stats, gsc, gbi, bufA);
    // fused QKV (bf16 compute, fp8 outputs): nt 0-3 -> q8, 4-7 -> k8, 8-11 -> v8^T
    gemm_kernel<0><<<dim3(32, 12, BB), 256, 0, stream>>>(bufA, BLC, CC, wbf, 0, CC, bcat,
                                                         q8, k8, v8, BLC, nullptr, nullptr, CC);
    // attention: P' = exp(QK^T*scale - 3) fp8 + rowsums; O = (P' V) / rowsum
    // MODE 1 serial 2-tile supertile: block does (nt, nt+16) -> grid (32, 16, BB)
    gemm8_kernel<1><<<dim3(32, 16, BB), 256, 0, stream>>>(q8, BLC, CC, k8, BLC, CC, scale,
                                                          S8, nullptr, (size_t)LL * LL, LL, CC, rowsum);
    gemm8_kernel<2><<<dim3(32, 4, BB), 256, 0, stream>>>(S8, (size_t)LL * LL, LL, v8, BLC, LL, 1.f,
                                                         nullptr, bufA, BLC, CC, LL, rowsum);
    // proj + residual + transposed f32 store
    gemm_kernel<3><<<dim3(32, 4, BB), 256, 0, stream>>>(bufA, BLC, CC, wbf + 3 * CC * CC, 0, CC,
                                                        bp, nullptr, nullptr, nullptr, 0, x, out, CC);
}